// Round 6
// baseline (2177.356 us; speedup 1.0000x reference)
//
#include <hip/hip_runtime.h>
#include <math.h>

// Problem constants
#define BB   4
#define SS   256
#define VV   64
#define LP1  11
#define HH   128
#define NHH  8
#define DHH  16
#define NLL  3
#define BSZ  1024   // BB*SS

typedef unsigned short u16;
typedef unsigned int   u32;

__device__ __forceinline__ float bfbits2f(u32 hi16) {
    u32 i = hi16 << 16; float f; __builtin_memcpy(&f, &i, 4); return f;
}
__device__ __forceinline__ u16 f2bf(float f) {
    u32 i; __builtin_memcpy(&i, &f, 4);
    return (u16)((i + 0x7fffu + ((i >> 16) & 1u)) >> 16);
}
// global-flag-branched load (isbf wave-uniform)
__device__ __forceinline__ float ldf(const void* p, size_t i, int isbf) {
    if (isbf) return bfbits2f(((const u16*)p)[i]);
    return ((const float*)p)[i];
}

// ---------- kernel S: global dtype sniff on mech_W (random, nonzero) -------
// f32 storage: low mantissa words decode to wild bf16 exponents w.h.p.
// bf16 storage of N(0,0.09) weights: all |v| < 1. P(f32 misclass) ~ 0.6^128.
__global__ __launch_bounds__(64) void k_sniff(const u16* __restrict__ probe,
                                              int* __restrict__ flags) {
    if (threadIdx.x == 0) {
        int wild = 0;
        for (int j = 0; j < 256; j++) {
            float v = bfbits2f(probe[j]);
            if (!(fabsf(v) < 1e8f)) wild = 1;   // catches inf/NaN too
        }
        flags[0] = wild ? 0 : 1;   // 1 = bf16 storage (and bf16 output)
    }
}

// ---------------- kernel 1: adj = sigmoid(adjacency_logits) ----------------
__global__ __launch_bounds__(256) void k_adj(const void* __restrict__ logits,
                                             float* __restrict__ adj,
                                             const int* __restrict__ flags) {
    int isbf = flags[0];
    int i = blockIdx.x * 256 + threadIdx.x;
    if (i < VV * VV * LP1) {
        float v = ldf(logits, i, isbf);
        adj[i] = 1.f / (1.f + expf(-v));
    }
}

// ---------------- kernel 2: z0[i, bt, h] ------------------------------------
// block = (bt, i), 128 threads (h). A[s], Bl[l] in LDS.
__global__ __launch_bounds__(128) void k_z0(const void* __restrict__ x,
                                            const float* __restrict__ adj,
                                            const void* __restrict__ var_emb,
                                            const void* __restrict__ temp_emb,
                                            float* __restrict__ z0,
                                            const int* __restrict__ flags) {
    int isbf = flags[0];
    int tid = threadIdx.x;
    int bt = blockIdx.x, i = blockIdx.y;
    int b = bt >> 8, t = bt & 255;
    __shared__ float A[VV];
    __shared__ float Bl[LP1];

    if (tid < VV) {
        int s = tid;
        float acc = 0.f;
        for (int l = 0; l < LP1; l++) {
            int tt = t - l;
            float xv = (tt >= 0) ? ldf(x, (size_t)(b * SS + tt) * VV + s, isbf) : 0.f;
            acc += xv * adj[(s * VV + i) * LP1 + l];
        }
        A[s] = acc;
    } else if (tid < VV + LP1) {
        int l = tid - VV;
        int tt = t - l;
        float acc = 0.f;
        if (tt >= 0) {
            for (int s = 0; s < VV; s++) {
                float xv = ldf(x, (size_t)(b * SS + tt) * VV + s, isbf);
                acc += xv * adj[(s * VV + i) * LP1 + l];
            }
        }
        Bl[l] = acc;
    }
    __syncthreads();

    int h = tid;
    float acc = 0.f;
    for (int s = 0; s < VV; s++) acc += A[s] * ldf(var_emb, (size_t)s * HH + h, isbf);
    for (int l = 0; l < LP1; l++) acc += Bl[l] * ldf(temp_emb, (size_t)l * HH + h, isbf);
    z0[((size_t)i * BSZ + bt) * HH + h] = acc;
}

// ---------------- kernel 3: generic per-variable linear ---------------------
// out[v,bt,k] = sum_h in[v,bt,h]*W[Wbase+v*Wvs+h*H+k] + bias[Bbase+v*Bvs+k]
// block = (bt, v), 128 threads (k). out f32 or internal-bf16 per out_bf16.
__global__ __launch_bounds__(128) void k_lin(const float* __restrict__ in,
                                             const void* __restrict__ W,
                                             const void* __restrict__ bias,
                                             void* __restrict__ out,
                                             size_t Wbase, size_t Wvs,
                                             size_t Bbase, size_t Bvs,
                                             int out_bf16,
                                             const int* __restrict__ flags) {
    int isbf = flags[0];
    int k = threadIdx.x;
    int bt = blockIdx.x, v = blockIdx.y;
    __shared__ float zrow[HH];
    size_t row = (size_t)v * BSZ + bt;
    zrow[k] = in[row * HH + k];
    __syncthreads();

    size_t wb = Wbase + (size_t)v * Wvs;
    float acc = ldf(bias, Bbase + (size_t)v * Bvs + k, isbf);
    for (int h = 0; h < HH; h++)
        acc += zrow[h] * ldf(W, wb + (size_t)h * HH + k, isbf);

    if (out_bf16) ((u16*)out)[row * HH + k] = f2bf(acc);
    else          ((float*)out)[row * HH + k] = acc;
}

// ---------------- kernel 4: LayerNorm + exact GELU, in place ----------------
__global__ __launch_bounds__(128) void k_lngelu(float* __restrict__ buf,
                                                const void* __restrict__ ln_g,
                                                const void* __restrict__ ln_b,
                                                int li,
                                                const int* __restrict__ flags) {
    int isbf = flags[0];
    int h = threadIdx.x;
    int bt = blockIdx.x, v = blockIdx.y;
    __shared__ float red[HH];
    size_t idx = ((size_t)v * BSZ + bt) * HH + h;
    float val = buf[idx];

    red[h] = val; __syncthreads();
    for (int s = 64; s > 0; s >>= 1) { if (h < s) red[h] += red[h + s]; __syncthreads(); }
    float mean = red[0] * (1.f / HH);
    __syncthreads();
    red[h] = val * val; __syncthreads();
    for (int s = 64; s > 0; s >>= 1) { if (h < s) red[h] += red[h + s]; __syncthreads(); }
    float var = red[0] * (1.f / HH) - mean * mean;

    float rstd = rsqrtf(var + 1e-5f);
    size_t pe = ((size_t)v * NLL + li) * HH + h;
    float g  = ldf(ln_g, pe, isbf);
    float b2 = ldf(ln_b, pe, isbf);
    float y = (val - mean) * rstd * g + b2;
    buf[idx] = 0.5f * y * (1.f + erff(y * 0.70710678118654752f));
}

// ---------------- kernel 5: attention, o overwrites Q in place --------------
// block = (bn, v): b = bn>>3, n = bn&7. 256 threads = query t.
// Q f32 (V,BS,H) with h = n*16+d ; K,V internal bf16 same layout.
__global__ __launch_bounds__(256) void k_attn(float* __restrict__ Q,
                                              const u16* __restrict__ K16,
                                              const u16* __restrict__ V16) {
    __shared__ float K_sh[SS * DHH];
    __shared__ float V_sh[SS * DHH];
    int tid = threadIdx.x;
    int bn = blockIdx.x, v = blockIdx.y;
    int b = bn >> 3, n = bn & 7;

    for (int p = tid; p < SS * DHH; p += 256) {
        int j = p >> 4, d = p & 15;
        size_t src = ((size_t)v * BSZ + b * SS + j) * HH + n * DHH + d;
        K_sh[p] = bfbits2f(K16[src]);
        V_sh[p] = bfbits2f(V16[src]);
    }
    float* qrow = Q + ((size_t)v * BSZ + b * SS + tid) * HH + n * DHH;
    const float4* qp = (const float4*)qrow;
    float4 q0 = qp[0], q1 = qp[1], q2 = qp[2], q3 = qp[3];
    __syncthreads();

    float m = -1e30f;
    for (int j = 0; j < SS; j++) {
        const float4* kr = (const float4*)&K_sh[j * DHH];
        float4 ka = kr[0], kb = kr[1], kc = kr[2], kd = kr[3];
        float s = q0.x * ka.x + q0.y * ka.y + q0.z * ka.z + q0.w * ka.w
                + q1.x * kb.x + q1.y * kb.y + q1.z * kb.z + q1.w * kb.w
                + q2.x * kc.x + q2.y * kc.y + q2.z * kc.z + q2.w * kc.w
                + q3.x * kd.x + q3.y * kd.y + q3.z * kd.z + q3.w * kd.w;
        m = fmaxf(m, s);
    }
    m *= 0.25f;

    float l = 0.f;
    float o[DHH];
    #pragma unroll
    for (int d = 0; d < DHH; d++) o[d] = 0.f;
    for (int j = 0; j < SS; j++) {
        const float4* kr = (const float4*)&K_sh[j * DHH];
        float4 ka = kr[0], kb = kr[1], kc = kr[2], kd = kr[3];
        float s = q0.x * ka.x + q0.y * ka.y + q0.z * ka.z + q0.w * ka.w
                + q1.x * kb.x + q1.y * kb.y + q1.z * kb.z + q1.w * kb.w
                + q2.x * kc.x + q2.y * kc.y + q2.z * kc.z + q2.w * kc.w
                + q3.x * kd.x + q3.y * kd.y + q3.z * kd.z + q3.w * kd.w;
        float w = __expf(s * 0.25f - m);
        l += w;
        #pragma unroll
        for (int d = 0; d < DHH; d++) o[d] += w * V_sh[j * DHH + d];
    }
    float inv = 1.f / l;
    #pragma unroll
    for (int d = 0; d < DHH; d++) qrow[d] = o[d] * inv;
}

// ---------------- kernel 6: output head (Wo then out_W) ---------------------
__global__ __launch_bounds__(128) void k_pred(const float* __restrict__ o,
                                              const void* __restrict__ Wo,
                                              const void* __restrict__ bo,
                                              const void* __restrict__ outW,
                                              const void* __restrict__ outb,
                                              void* __restrict__ out,
                                              const int* __restrict__ flags) {
    int isbf = flags[0];
    int k = threadIdx.x;
    int bt = blockIdx.x, v = blockIdx.y;
    __shared__ float orow[HH];
    __shared__ float red[HH];
    size_t row = (size_t)v * BSZ + bt;
    orow[k] = o[row * HH + k];
    __syncthreads();

    float acc = ldf(bo, (size_t)v * HH + k, isbf);
    size_t wb = (size_t)v * HH * HH;
    for (int h = 0; h < HH; h++)
        acc += orow[h] * ldf(Wo, wb + (size_t)h * HH + k, isbf);
    red[k] = acc * ldf(outW, (size_t)v * HH + k, isbf);
    __syncthreads();
    for (int s = 64; s > 0; s >>= 1) { if (k < s) red[k] += red[k + s]; __syncthreads(); }
    if (k == 0) {
        float pred = red[0] + ldf(outb, v, isbf);
        size_t oi = (size_t)bt * VV + v;
        if (isbf) ((u16*)out)[oi] = f2bf(pred);   // output dtype follows inputs
        else      ((float*)out)[oi] = pred;
    }
}

extern "C" void kernel_launch(void* const* d_in, const int* in_sizes, int n_in,
                              void* d_out, int out_size, void* d_ws, size_t ws_size,
                              hipStream_t stream) {
    (void)out_size; (void)ws_size;

    // ---- resolve input permutation from in_sizes (host-side, capture-safe) ----
    // logical order: x,adjl,var,temp,mechW,mechb,lng,lnb,Wq,Wk,Wv,Wo,bq,bk,bv,bo,outW,outb
    static const int dict_sizes[18]  = {65536,45056,8192,1408,3145728,24576,24576,24576,
                                        1048576,1048576,1048576,1048576,8192,8192,8192,8192,8192,64};
    // jax.tree_flatten sorts dict keys (case-sensitive):
    // Wk,Wo,Wq,Wv,adjl,bk,bo,bq,bv,ln_b,ln_g,mech_W,mech_b,out_W,out_b,temp,var,x
    static const int alpha_sizes[18] = {1048576,1048576,1048576,1048576,45056,8192,8192,8192,
                                        8192,24576,24576,3145728,24576,8192,64,1408,8192,65536};
    // alpha_pos[logical] = index in alphabetical order
    static const int alpha_pos[18]   = {17,4,16,15,11,12,10,9,2,0,3,1,7,5,8,6,13,14};
    // names in alphabetical order, as logical indices (for fallback)
    static const int alpha_logical[18] = {9,11,8,10,1,13,15,12,14,7,6,4,5,16,17,3,2,0};

    const void* in[18];
    bool is_dict = (n_in == 18), is_alpha = (n_in == 18);
    for (int i = 0; i < 18 && i < n_in; i++) {
        if (in_sizes[i] != dict_sizes[i])  is_dict = false;
        if (in_sizes[i] != alpha_sizes[i]) is_alpha = false;
    }
    if (is_dict) {
        for (int i = 0; i < 18; i++) in[i] = d_in[i];
    } else if (is_alpha) {
        for (int i = 0; i < 18; i++) in[i] = d_in[alpha_pos[i]];
    } else {
        // greedy size-class match, consuming inputs in order, logical slots in
        // alphabetical (tree_flatten) order
        bool used[18] = {false};
        for (int a = 0; a < 18; a++) {
            int lg = alpha_logical[a];
            for (int i = 0; i < n_in && i < 18; i++) {
                if (!used[i] && in_sizes[i] == dict_sizes[lg]) {
                    in[lg] = d_in[i]; used[i] = true; break;
                }
            }
        }
    }

    const void* x        = in[0];
    const void* adjl     = in[1];
    const void* var_emb  = in[2];
    const void* temp_emb = in[3];
    const void* mechW    = in[4];
    const void* mechb    = in[5];
    const void* lng      = in[6];
    const void* lnb      = in[7];
    const void* Wq       = in[8];
    const void* Wk       = in[9];
    const void* Wv       = in[10];
    const void* Wo       = in[11];
    const void* bq       = in[12];
    const void* bk       = in[13];
    const void* bv       = in[14];
    const void* bo       = in[15];
    const void* outW     = in[16];
    const void* outb     = in[17];

    // workspace (floats): flags | adj | zA | zB | K16 | V16  ~= 96.2 MB
    float* ws    = (float*)d_ws;
    int*   flags = (int*)ws;                  // 32 slots
    float* adj   = ws + 32;                   // 45056
    float* zA    = ws + 45120;                // 8388608 (V,BS,H) f32
    float* zB    = zA + 8388608;              // 8388608
    u16*   K16   = (u16*)(zB + 8388608);      // 8388608 u16
    u16*   V16   = K16 + 8388608;             // 8388608 u16

    const size_t WH2 = (size_t)HH * HH;       // 16384

    k_sniff<<<dim3(1), dim3(64), 0, stream>>>((const u16*)mechW, flags);
    k_adj  <<<dim3(176), dim3(256), 0, stream>>>(adjl, adj, flags);
    k_z0   <<<dim3(BSZ, VV), dim3(128), 0, stream>>>(x, adj, var_emb, temp_emb, zA, flags);

    // mech layers: 0: zA->zB, 1: zB->zA, 2: zA->zB (LN+GELU in place)
    k_lin   <<<dim3(BSZ, VV), dim3(128), 0, stream>>>(zA, mechW, mechb, zB,
              0 * WH2, NLL * WH2, 0 * HH, NLL * HH, 0, flags);
    k_lngelu<<<dim3(BSZ, VV), dim3(128), 0, stream>>>(zB, lng, lnb, 0, flags);
    k_lin   <<<dim3(BSZ, VV), dim3(128), 0, stream>>>(zB, mechW, mechb, zA,
              1 * WH2, NLL * WH2, 1 * HH, NLL * HH, 0, flags);
    k_lngelu<<<dim3(BSZ, VV), dim3(128), 0, stream>>>(zA, lng, lnb, 1, flags);
    k_lin   <<<dim3(BSZ, VV), dim3(128), 0, stream>>>(zA, mechW, mechb, zB,
              2 * WH2, NLL * WH2, 2 * HH, NLL * HH, 0, flags);
    k_lngelu<<<dim3(BSZ, VV), dim3(128), 0, stream>>>(zB, lng, lnb, 2, flags);

    // QKV from zB: Q->zA (f32), K/V->internal bf16
    k_lin<<<dim3(BSZ, VV), dim3(128), 0, stream>>>(zB, Wq, bq, zA,  0, WH2, 0, HH, 0, flags);
    k_lin<<<dim3(BSZ, VV), dim3(128), 0, stream>>>(zB, Wk, bk, K16, 0, WH2, 0, HH, 1, flags);
    k_lin<<<dim3(BSZ, VV), dim3(128), 0, stream>>>(zB, Wv, bv, V16, 0, WH2, 0, HH, 1, flags);

    // attention in place over Q (zA)
    k_attn<<<dim3(BB * NHH, VV), dim3(256), 0, stream>>>(zA, K16, V16);

    // output head
    k_pred<<<dim3(BSZ, VV), dim3(128), 0, stream>>>(zA, Wo, bo, outW, outb,
                                                    d_out, flags);
}

// Round 7
// 772.701 us; speedup vs baseline: 2.8179x; 2.8179x over previous
//
#include <hip/hip_runtime.h>
#include <math.h>

// Problem constants
#define BB   4
#define SS   256
#define VV   64
#define LP1  11
#define HH   128
#define NHH  8
#define DHH  16
#define NLL  3
#define BSZ  1024   // BB*SS

typedef unsigned short u16;
typedef unsigned int   u32;

__device__ __forceinline__ float bfbits2f(u32 hi16) {
    u32 i = hi16 << 16; float f; __builtin_memcpy(&f, &i, 4); return f;
}
__device__ __forceinline__ float b2f_lo(u32 u) { return bfbits2f(u & 0xffffu); }
__device__ __forceinline__ float b2f_hi(u32 u) {
    u32 i = u & 0xffff0000u; float f; __builtin_memcpy(&f, &i, 4); return f;
}
__device__ __forceinline__ u16 f2bf(float f) {
    u32 i; __builtin_memcpy(&i, &f, 4);
    return (u16)((i + 0x7fffu + ((i >> 16) & 1u)) >> 16);
}
// global-flag-branched scalar load (isbf wave-uniform)
__device__ __forceinline__ float ldf(const void* p, size_t i, int isbf) {
    if (isbf) return bfbits2f(((const u16*)p)[i]);
    return ((const float*)p)[i];
}
// stage n elems (mult of 4; src 8B-aligned) into LDS as f32
__device__ __forceinline__ void stage(float* dst, const void* src, int n, int isbf,
                                      int tid, int nt) {
    if (isbf) {
        const uint2* s = (const uint2*)src;
        for (int p = tid; p < n / 4; p += nt) {
            uint2 u = s[p]; float4 f;
            f.x = b2f_lo(u.x); f.y = b2f_hi(u.x); f.z = b2f_lo(u.y); f.w = b2f_hi(u.y);
            ((float4*)dst)[p] = f;
        }
    } else {
        const float4* s = (const float4*)src;
        for (int p = tid; p < n / 4; p += nt) ((float4*)dst)[p] = s[p];
    }
}

// ---------- kernel S: global dtype sniff on mech_W (random, nonzero) -------
__global__ __launch_bounds__(64) void k_sniff(const u16* __restrict__ probe,
                                              int* __restrict__ flags) {
    if (threadIdx.x == 0) {
        int wild = 0;
        for (int j = 0; j < 256; j++) {
            float v = bfbits2f(probe[j]);
            if (!(fabsf(v) < 1e8f)) wild = 1;
        }
        flags[0] = wild ? 0 : 1;   // 1 = bf16 storage (and bf16 output)
    }
}

// ---------------- kernel 1: adj = sigmoid(adjacency_logits) ----------------
__global__ __launch_bounds__(256) void k_adj(const void* __restrict__ logits,
                                             float* __restrict__ adj,
                                             const int* __restrict__ flags) {
    int isbf = flags[0];
    int i = blockIdx.x * 256 + threadIdx.x;
    if (i < VV * VV * LP1) {
        float v = ldf(logits, i, isbf);
        adj[i] = 1.f / (1.f + expf(-v));
    }
}

// ---------------- kernel 0b: fold Wo into output head ----------------------
// wfused[v,h] = sum_k Wo[v,h,k]*outW[v,k]; bfused[v] = dot(bo[v],outW[v])+outb[v]
__global__ __launch_bounds__(128) void k_fuse(const void* __restrict__ Wo,
                                              const void* __restrict__ outW,
                                              const void* __restrict__ bo,
                                              const void* __restrict__ outb,
                                              float* __restrict__ wfused,
                                              float* __restrict__ bfused,
                                              const int* __restrict__ flags) {
    int isbf = flags[0];
    int v = blockIdx.x; int h = threadIdx.x;
    __shared__ float ow[HH];
    __shared__ float red[HH];
    ow[h] = ldf(outW, (size_t)v * HH + h, isbf);
    __syncthreads();
    size_t wb = ((size_t)v * HH + h) * HH;
    float acc = 0.f;
    #pragma unroll 8
    for (int k = 0; k < HH; k++) acc += ldf(Wo, wb + k, isbf) * ow[k];
    wfused[v * HH + h] = acc;
    red[h] = ldf(bo, (size_t)v * HH + h, isbf) * ow[h];
    __syncthreads();
    for (int s = 64; s > 0; s >>= 1) { if (h < s) red[h] += red[h + s]; __syncthreads(); }
    if (h == 0) bfused[v] = red[0] + ldf(outb, v, isbf);
}

// ---------------- kernel 2: causal input z0 (V, BS, H), tiled --------------
// block per bt, 256 threads.
__global__ __launch_bounds__(256) void k_causal(const void* __restrict__ x,
                                                const float* __restrict__ adj,
                                                const void* __restrict__ var_emb,
                                                const void* __restrict__ temp_emb,
                                                float* __restrict__ z0,
                                                const int* __restrict__ flags) {
    __shared__ float xl[LP1][VV];        // xl[l][s] = x[b, t-l, s]
    __shared__ float A_sh[VV][VV + 1];   // A[i][s]
    __shared__ float Bl_sh[VV][12];      // Bl[i][l]
    __shared__ float var_sh[VV * HH];
    __shared__ float temp_sh[LP1 * HH];
    int isbf = flags[0];
    int tid = threadIdx.x;
    int bt = blockIdx.x; int b = bt >> 8; int t = bt & 255;

    stage(var_sh, var_emb, VV * HH, isbf, tid, 256);
    stage(temp_sh, temp_emb, LP1 * HH, isbf, tid, 256);
    for (int p = tid; p < LP1 * VV; p += 256) {
        int l = p >> 6, s = p & 63; int tt = t - l;
        xl[l][s] = (tt >= 0) ? ldf(x, (size_t)(b * SS + tt) * VV + s, isbf) : 0.f;
    }
    __syncthreads();

    // A[i][s] = sum_l xl[l][s]*adj[s,i,l]
    for (int p = tid; p < VV * VV; p += 256) {
        int i = p & 63, s = p >> 6;
        const float* ap = adj + (s * VV + i) * LP1;
        float acc = 0.f;
        #pragma unroll
        for (int l = 0; l < LP1; l++) acc += xl[l][s] * ap[l];
        A_sh[i][s] = acc;
    }
    // Bl[i][l] = sum_s xl[l][s]*adj[s,i,l]
    for (int p = tid; p < VV * LP1; p += 256) {
        int i = p & 63, l = p >> 6;
        float acc = 0.f;
        for (int s = 0; s < VV; s++) acc += xl[l][s] * adj[(s * VV + i) * LP1 + l];
        Bl_sh[i][l] = acc;
    }
    __syncthreads();

    // z0[i, bt, h] = sum_s A[i][s]*var[s][h] + sum_l Bl[i][l]*temp[l][h]
    for (int o4 = tid; o4 < VV * HH / 4; o4 += 256) {
        int i = o4 >> 5; int h0 = (o4 & 31) * 4;
        float4 acc = make_float4(0.f, 0.f, 0.f, 0.f);
        for (int s = 0; s < VV; s++) {
            float a = A_sh[i][s];
            const float4 vv4 = *(const float4*)&var_sh[s * HH + h0];
            acc.x += a * vv4.x; acc.y += a * vv4.y; acc.z += a * vv4.z; acc.w += a * vv4.w;
        }
        #pragma unroll
        for (int l = 0; l < LP1; l++) {
            float bl = Bl_sh[i][l];
            const float4 tv = *(const float4*)&temp_sh[l * HH + h0];
            acc.x += bl * tv.x; acc.y += bl * tv.y; acc.z += bl * tv.z; acc.w += bl * tv.w;
        }
        *(float4*)&z0[((size_t)i * BSZ + bt) * HH + h0] = acc;
    }
}

// ---------------- kernel 3: tiled Linear + LN + GELU -----------------------
// grid (16,64), 256 threads; tile = 64 tokens x 128 cols; LDS 48KB
__global__ __launch_bounds__(256) void k_mech(const float* __restrict__ zin,
                                              float* __restrict__ zout,
                                              const void* __restrict__ mechW,
                                              const void* __restrict__ mechb,
                                              const void* __restrict__ lng,
                                              const void* __restrict__ lnb,
                                              int li,
                                              const int* __restrict__ flags) {
    __shared__ float zin_sh[64 * HH];   // 32KB
    __shared__ float W_sh[32 * HH];     // 16KB
    int isbf = flags[0];
    int tid = threadIdx.x; int tile = blockIdx.x; int v = blockIdx.y;
    const float* zb = zin + ((size_t)v * BSZ + tile * 64) * HH;
    for (int p4 = tid; p4 < 64 * HH / 4; p4 += 256)
        ((float4*)zin_sh)[p4] = ((const float4*)zb)[p4];

    int rg = tid >> 4, cg = tid & 15; int r0 = rg * 4, k0 = cg * 8;
    float acc[4][8];
    #pragma unroll
    for (int i = 0; i < 4; i++)
        #pragma unroll
        for (int j = 0; j < 8; j++) acc[i][j] = 0.f;

    size_t Wb_e = ((size_t)v * NLL + li) * HH * HH;
    for (int c = 0; c < 4; c++) {
        __syncthreads();
        const void* Wc = isbf ? (const void*)((const u16*)mechW + Wb_e + c * 32 * HH)
                              : (const void*)((const float*)mechW + Wb_e + c * 32 * HH);
        stage(W_sh, Wc, 32 * HH, isbf, tid, 256);
        __syncthreads();
        #pragma unroll 4
        for (int hh = 0; hh < 32; hh += 2) {
            float4 p0 = *(const float4*)&W_sh[hh * HH + k0];
            float4 p1 = *(const float4*)&W_sh[hh * HH + k0 + 4];
            float4 p2 = *(const float4*)&W_sh[(hh + 1) * HH + k0];
            float4 p3 = *(const float4*)&W_sh[(hh + 1) * HH + k0 + 4];
            #pragma unroll
            for (int i = 0; i < 4; i++) {
                float2 aa = *(const float2*)&zin_sh[(r0 + i) * HH + c * 32 + hh];
                acc[i][0] += aa.x * p0.x + aa.y * p2.x;
                acc[i][1] += aa.x * p0.y + aa.y * p2.y;
                acc[i][2] += aa.x * p0.z + aa.y * p2.z;
                acc[i][3] += aa.x * p0.w + aa.y * p2.w;
                acc[i][4] += aa.x * p1.x + aa.y * p3.x;
                acc[i][5] += aa.x * p1.y + aa.y * p3.y;
                acc[i][6] += aa.x * p1.z + aa.y * p3.z;
                acc[i][7] += aa.x * p1.w + aa.y * p3.w;
            }
        }
    }

    float bias[8], g[8], b2[8];
    size_t pe = ((size_t)v * NLL + li) * HH + k0;
    #pragma unroll
    for (int j = 0; j < 8; j++) {
        bias[j] = ldf(mechb, pe + j, isbf);
        g[j]    = ldf(lng,   pe + j, isbf);
        b2[j]   = ldf(lnb,   pe + j, isbf);
    }

    #pragma unroll
    for (int i = 0; i < 4; i++) {
        float sum = 0.f, sq = 0.f;
        #pragma unroll
        for (int j = 0; j < 8; j++) {
            float val = acc[i][j] + bias[j];
            acc[i][j] = val; sum += val; sq += val * val;
        }
        #pragma unroll
        for (int m = 1; m < 16; m <<= 1) {
            sum += __shfl_xor(sum, m);
            sq  += __shfl_xor(sq, m);
        }
        float mean = sum * (1.f / HH);
        float var  = sq * (1.f / HH) - mean * mean;
        float rstd = rsqrtf(var + 1e-5f);
        float ov[8];
        #pragma unroll
        for (int j = 0; j < 8; j++) {
            float y = (acc[i][j] - mean) * rstd * g[j] + b2[j];
            ov[j] = 0.5f * y * (1.f + erff(y * 0.70710678118654752f));
        }
        float4 o0 = make_float4(ov[0], ov[1], ov[2], ov[3]);
        float4 o1 = make_float4(ov[4], ov[5], ov[6], ov[7]);
        float* op = zout + ((size_t)v * BSZ + tile * 64 + r0 + i) * HH + k0;
        *(float4*)op = o0; *(float4*)(op + 4) = o1;
    }
}

// ---------------- kernel 4: fused QKV projection ---------------------------
// Q -> f32 (V,BS,H); K,V -> bf16 (V,BS,H)
__global__ __launch_bounds__(256) void k_qkv(const float* __restrict__ zin,
                                             const void* __restrict__ Wq,
                                             const void* __restrict__ Wk,
                                             const void* __restrict__ Wv,
                                             const void* __restrict__ bq,
                                             const void* __restrict__ bk,
                                             const void* __restrict__ bv,
                                             float* __restrict__ Q,
                                             u16* __restrict__ K16,
                                             u16* __restrict__ V16,
                                             const int* __restrict__ flags) {
    __shared__ float zin_sh[64 * HH];
    __shared__ float W_sh[32 * HH];
    int isbf = flags[0];
    int tid = threadIdx.x; int tile = blockIdx.x; int v = blockIdx.y;
    const float* zb = zin + ((size_t)v * BSZ + tile * 64) * HH;
    for (int p4 = tid; p4 < 64 * HH / 4; p4 += 256)
        ((float4*)zin_sh)[p4] = ((const float4*)zb)[p4];

    int rg = tid >> 4, cg = tid & 15; int r0 = rg * 4, k0 = cg * 8;

    for (int w = 0; w < 3; w++) {
        const void* Wp = (w == 0 ? Wq : (w == 1 ? Wk : Wv));
        const void* bp = (w == 0 ? bq : (w == 1 ? bk : bv));
        size_t Wb_e = (size_t)v * HH * HH;
        float acc[4][8];
        #pragma unroll
        for (int i = 0; i < 4; i++)
            #pragma unroll
            for (int j = 0; j < 8; j++) acc[i][j] = 0.f;

        for (int c = 0; c < 4; c++) {
            __syncthreads();
            const void* Wc = isbf ? (const void*)((const u16*)Wp + Wb_e + c * 32 * HH)
                                  : (const void*)((const float*)Wp + Wb_e + c * 32 * HH);
            stage(W_sh, Wc, 32 * HH, isbf, tid, 256);
            __syncthreads();
            #pragma unroll 4
            for (int hh = 0; hh < 32; hh += 2) {
                float4 p0 = *(const float4*)&W_sh[hh * HH + k0];
                float4 p1 = *(const float4*)&W_sh[hh * HH + k0 + 4];
                float4 p2 = *(const float4*)&W_sh[(hh + 1) * HH + k0];
                float4 p3 = *(const float4*)&W_sh[(hh + 1) * HH + k0 + 4];
                #pragma unroll
                for (int i = 0; i < 4; i++) {
                    float2 aa = *(const float2*)&zin_sh[(r0 + i) * HH + c * 32 + hh];
                    acc[i][0] += aa.x * p0.x + aa.y * p2.x;
                    acc[i][1] += aa.x * p0.y + aa.y * p2.y;
                    acc[i][2] += aa.x * p0.z + aa.y * p2.z;
                    acc[i][3] += aa.x * p0.w + aa.y * p2.w;
                    acc[i][4] += aa.x * p1.x + aa.y * p3.x;
                    acc[i][5] += aa.x * p1.y + aa.y * p3.y;
                    acc[i][6] += aa.x * p1.z + aa.y * p3.z;
                    acc[i][7] += aa.x * p1.w + aa.y * p3.w;
                }
            }
        }
        float bias[8];
        #pragma unroll
        for (int j = 0; j < 8; j++) bias[j] = ldf(bp, (size_t)v * HH + k0 + j, isbf);
        #pragma unroll
        for (int i = 0; i < 4; i++) {
            size_t row = (size_t)v * BSZ + tile * 64 + r0 + i;
            float s[8];
            #pragma unroll
            for (int j = 0; j < 8; j++) s[j] = acc[i][j] + bias[j];
            if (w == 0) {
                float* op = Q + row * HH + k0;
                *(float4*)op     = make_float4(s[0], s[1], s[2], s[3]);
                *(float4*)(op+4) = make_float4(s[4], s[5], s[6], s[7]);
            } else {
                u16* o16 = (w == 1 ? K16 : V16) + row * HH + k0;
                uint4 pk;
                pk.x = (u32)f2bf(s[0]) | ((u32)f2bf(s[1]) << 16);
                pk.y = (u32)f2bf(s[2]) | ((u32)f2bf(s[3]) << 16);
                pk.z = (u32)f2bf(s[4]) | ((u32)f2bf(s[5]) << 16);
                pk.w = (u32)f2bf(s[6]) | ((u32)f2bf(s[7]) << 16);
                *(uint4*)o16 = pk;
            }
        }
    }
}

// ---------------- kernel 5: attention, o overwrites Q in place --------------
__global__ __launch_bounds__(256) void k_attn(float* __restrict__ Q,
                                              const u16* __restrict__ K16,
                                              const u16* __restrict__ V16) {
    __shared__ float K_sh[SS * DHH];
    __shared__ float V_sh[SS * DHH];
    int tid = threadIdx.x;
    int bn = blockIdx.x, v = blockIdx.y;
    int b = bn >> 3, n = bn & 7;

    for (int p = tid; p < SS * DHH; p += 256) {
        int j = p >> 4, d = p & 15;
        size_t src = ((size_t)v * BSZ + b * SS + j) * HH + n * DHH + d;
        K_sh[p] = bfbits2f(K16[src]);
        V_sh[p] = bfbits2f(V16[src]);
    }
    float* qrow = Q + ((size_t)v * BSZ + b * SS + tid) * HH + n * DHH;
    const float4* qp = (const float4*)qrow;
    float4 q0 = qp[0], q1 = qp[1], q2 = qp[2], q3 = qp[3];
    __syncthreads();

    float m = -1e30f;
    for (int j = 0; j < SS; j++) {
        const float4* kr = (const float4*)&K_sh[j * DHH];
        float4 ka = kr[0], kb = kr[1], kc = kr[2], kd = kr[3];
        float s = q0.x * ka.x + q0.y * ka.y + q0.z * ka.z + q0.w * ka.w
                + q1.x * kb.x + q1.y * kb.y + q1.z * kb.z + q1.w * kb.w
                + q2.x * kc.x + q2.y * kc.y + q2.z * kc.z + q2.w * kc.w
                + q3.x * kd.x + q3.y * kd.y + q3.z * kd.z + q3.w * kd.w;
        m = fmaxf(m, s);
    }
    m *= 0.25f;

    float l = 0.f;
    float o[DHH];
    #pragma unroll
    for (int d = 0; d < DHH; d++) o[d] = 0.f;
    for (int j = 0; j < SS; j++) {
        const float4* kr = (const float4*)&K_sh[j * DHH];
        float4 ka = kr[0], kb = kr[1], kc = kr[2], kd = kr[3];
        float s = q0.x * ka.x + q0.y * ka.y + q0.z * ka.z + q0.w * ka.w
                + q1.x * kb.x + q1.y * kb.y + q1.z * kb.z + q1.w * kb.w
                + q2.x * kc.x + q2.y * kc.y + q2.z * kc.z + q2.w * kc.w
                + q3.x * kd.x + q3.y * kd.y + q3.z * kd.z + q3.w * kd.w;
        float w = __expf(s * 0.25f - m);
        l += w;
        #pragma unroll
        for (int d = 0; d < DHH; d++) o[d] += w * V_sh[j * DHH + d];
    }
    float inv = 1.f / l;
    #pragma unroll
    for (int d = 0; d < DHH; d++) qrow[d] = o[d] * inv;
}

// ---------------- kernel 6: fused output head ------------------------------
// grid (BB, VV), 256 threads = t; pred[bt,v] = dot(o[v,bt,:], wfused[v,:]) + bfused[v]
__global__ __launch_bounds__(256) void k_final(const float* __restrict__ o,
                                               const float* __restrict__ wfused,
                                               const float* __restrict__ bfused,
                                               void* __restrict__ out,
                                               const int* __restrict__ flags) {
    __shared__ float wf[HH];
    int isbf = flags[0];
    int tid = threadIdx.x; int b = blockIdx.x; int v = blockIdx.y;
    if (tid < HH) wf[tid] = wfused[v * HH + tid];
    __syncthreads();
    int bt = b * SS + tid;
    const float* orow = o + ((size_t)v * BSZ + bt) * HH;
    float acc = 0.f;
    #pragma unroll 8
    for (int h4 = 0; h4 < HH / 4; h4++) {
        float4 ov = ((const float4*)orow)[h4];
        const float4 wv = *(const float4*)&wf[h4 * 4];
        acc += ov.x * wv.x + ov.y * wv.y + ov.z * wv.z + ov.w * wv.w;
    }
    float pred = acc + bfused[v];
    size_t oi = (size_t)bt * VV + v;
    if (isbf) ((u16*)out)[oi] = f2bf(pred);
    else      ((float*)out)[oi] = pred;
}

extern "C" void kernel_launch(void* const* d_in, const int* in_sizes, int n_in,
                              void* d_out, int out_size, void* d_ws, size_t ws_size,
                              hipStream_t stream) {
    (void)out_size; (void)ws_size;

    // ---- resolve input permutation from in_sizes (host-side, capture-safe) ----
    static const int dict_sizes[18]  = {65536,45056,8192,1408,3145728,24576,24576,24576,
                                        1048576,1048576,1048576,1048576,8192,8192,8192,8192,8192,64};
    static const int alpha_sizes[18] = {1048576,1048576,1048576,1048576,45056,8192,8192,8192,
                                        8192,24576,24576,3145728,24576,8192,64,1408,8192,65536};
    static const int alpha_pos[18]   = {17,4,16,15,11,12,10,9,2,0,3,1,7,5,8,6,13,14};
    static const int alpha_logical[18] = {9,11,8,10,1,13,15,12,14,7,6,4,5,16,17,3,2,0};

    const void* in[18];
    bool is_dict = (n_in == 18), is_alpha = (n_in == 18);
    for (int i = 0; i < 18 && i < n_in; i++) {
        if (in_sizes[i] != dict_sizes[i])  is_dict = false;
        if (in_sizes[i] != alpha_sizes[i]) is_alpha = false;
    }
    if (is_dict) {
        for (int i = 0; i < 18; i++) in[i] = d_in[i];
    } else if (is_alpha) {
        for (int i = 0; i < 18; i++) in[i] = d_in[alpha_pos[i]];
    } else {
        bool used[18] = {false};
        for (int a = 0; a < 18; a++) {
            int lg = alpha_logical[a];
            for (int i = 0; i < n_in && i < 18; i++) {
                if (!used[i] && in_sizes[i] == dict_sizes[lg]) {
                    in[lg] = d_in[i]; used[i] = true; break;
                }
            }
        }
    }

    const void* x        = in[0];
    const void* adjl     = in[1];
    const void* var_emb  = in[2];
    const void* temp_emb = in[3];
    const void* mechW    = in[4];
    const void* mechb    = in[5];
    const void* lng      = in[6];
    const void* lnb      = in[7];
    const void* Wq       = in[8];
    const void* Wk       = in[9];
    const void* Wv       = in[10];
    const void* Wo       = in[11];
    const void* bq       = in[12];
    const void* bk       = in[13];
    const void* bv       = in[14];
    const void* bo       = in[15];
    const void* outW     = in[16];
    const void* outb     = in[17];

    // workspace (floats): flags | adj | wfused | bfused | zA | zB | K16 | V16
    float* ws     = (float*)d_ws;
    int*   flags  = (int*)ws;                 // 32 slots
    float* adj    = ws + 32;                  // 45056
    float* wfused = ws + 45120;               // 8192
    float* bfused = wfused + 8192;            // 64
    float* zA     = ws + 53440;               // 8388608 (V,BS,H) f32
    float* zB     = zA + 8388608;             // 8388608
    u16*   K16    = (u16*)(zB + 8388608);     // 8388608 u16
    u16*   V16    = K16 + 8388608;            // 8388608 u16

    k_sniff <<<dim3(1),      dim3(64),  0, stream>>>((const u16*)mechW, flags);
    k_adj   <<<dim3(176),    dim3(256), 0, stream>>>(adjl, adj, flags);
    k_fuse  <<<dim3(64),     dim3(128), 0, stream>>>(Wo, outW, bo, outb, wfused, bfused, flags);
    k_causal<<<dim3(BSZ),    dim3(256), 0, stream>>>(x, adj, var_emb, temp_emb, zA, flags);

    k_mech  <<<dim3(16, 64), dim3(256), 0, stream>>>(zA, zB, mechW, mechb, lng, lnb, 0, flags);
    k_mech  <<<dim3(16, 64), dim3(256), 0, stream>>>(zB, zA, mechW, mechb, lng, lnb, 1, flags);
    k_mech  <<<dim3(16, 64), dim3(256), 0, stream>>>(zA, zB, mechW, mechb, lng, lnb, 2, flags);

    k_qkv   <<<dim3(16, 64), dim3(256), 0, stream>>>(zB, Wq, Wk, Wv, bq, bk, bv,
                                                     zA, K16, V16, flags);
    k_attn  <<<dim3(BB * NHH, VV), dim3(256), 0, stream>>>(zA, K16, V16);
    k_final <<<dim3(BB, VV), dim3(256), 0, stream>>>(zA, wfused, bfused, d_out, flags);
}

// Round 8
// 694.691 us; speedup vs baseline: 3.1343x; 1.1123x over previous
//
#include <hip/hip_runtime.h>
#include <math.h>

// Problem constants
#define BB   4
#define SS   256
#define VV   64
#define LP1  11
#define HH   128
#define NHH  8
#define DHH  16
#define NLL  3
#define BSZ  1024   // BB*SS

typedef unsigned short u16;
typedef unsigned int   u32;
typedef __attribute__((ext_vector_type(8))) short s16x8;   // 8 bf16 (4 VGPR)
typedef __attribute__((ext_vector_type(4))) float f32x4;   // MFMA acc

__device__ __forceinline__ float bfbits2f(u32 hi16) {
    u32 i = hi16 << 16; float f; __builtin_memcpy(&f, &i, 4); return f;
}
__device__ __forceinline__ u16 f2bf(float f) {
    u32 i; __builtin_memcpy(&i, &f, 4);
    return (u16)((i + 0x7fffu + ((i >> 16) & 1u)) >> 16);
}
__device__ __forceinline__ float ldf(const void* p, size_t i, int isbf) {
    if (isbf) return bfbits2f(((const u16*)p)[i]);
    return ((const float*)p)[i];
}
// stage n elems (mult of 4; src 8B-aligned) into LDS as f32
__device__ __forceinline__ void stage(float* dst, const void* src, int n, int isbf,
                                      int tid, int nt) {
    if (isbf) {
        const uint2* s = (const uint2*)src;
        for (int p = tid; p < n / 4; p += nt) {
            uint2 u = s[p]; float4 f;
            f.x = bfbits2f(u.x & 0xffffu); f.y = bfbits2f(u.x >> 16);
            f.z = bfbits2f(u.y & 0xffffu); f.w = bfbits2f(u.y >> 16);
            ((float4*)dst)[p] = f;
        }
    } else {
        const float4* s = (const float4*)src;
        for (int p = tid; p < n / 4; p += nt) ((float4*)dst)[p] = s[p];
    }
}

// ---------- kernel S: global dtype sniff on mech_W (random, nonzero) -------
__global__ __launch_bounds__(64) void k_sniff(const u16* __restrict__ probe,
                                              int* __restrict__ flags) {
    if (threadIdx.x == 0) {
        int wild = 0;
        for (int j = 0; j < 256; j++) {
            float v = bfbits2f(probe[j]);
            if (!(fabsf(v) < 1e8f)) wild = 1;
        }
        flags[0] = wild ? 0 : 1;   // 1 = bf16 storage (and bf16 output)
    }
}

// ---------------- kernel 1: adj = sigmoid(adjacency_logits) ----------------
__global__ __launch_bounds__(256) void k_adj(const void* __restrict__ logits,
                                             float* __restrict__ adj,
                                             const int* __restrict__ flags) {
    int isbf = flags[0];
    int i = blockIdx.x * 256 + threadIdx.x;
    if (i < VV * VV * LP1) {
        float v = ldf(logits, i, isbf);
        adj[i] = 1.f / (1.f + expf(-v));
    }
}

// ---------------- kernel 0b: fold Wo into output head ----------------------
__global__ __launch_bounds__(128) void k_fuse(const void* __restrict__ Wo,
                                              const void* __restrict__ outW,
                                              const void* __restrict__ bo,
                                              const void* __restrict__ outb,
                                              float* __restrict__ wfused,
                                              float* __restrict__ bfused,
                                              const int* __restrict__ flags) {
    int isbf = flags[0];
    int v = blockIdx.x; int h = threadIdx.x;
    __shared__ float ow[HH];
    __shared__ float red[HH];
    ow[h] = ldf(outW, (size_t)v * HH + h, isbf);
    __syncthreads();
    size_t wb = ((size_t)v * HH + h) * HH;
    float acc = 0.f;
    #pragma unroll 8
    for (int k = 0; k < HH; k++) acc += ldf(Wo, wb + k, isbf) * ow[k];
    wfused[v * HH + h] = acc;
    red[h] = ldf(bo, (size_t)v * HH + h, isbf) * ow[h];
    __syncthreads();
    for (int s = 64; s > 0; s >>= 1) { if (h < s) red[h] += red[h + s]; __syncthreads(); }
    if (h == 0) bfused[v] = red[0] + ldf(outb, v, isbf);
}

// ---------------- kernel 2: causal input z0 (V, BS, H), tiled --------------
__global__ __launch_bounds__(256) void k_causal(const void* __restrict__ x,
                                                const float* __restrict__ adj,
                                                const void* __restrict__ var_emb,
                                                const void* __restrict__ temp_emb,
                                                float* __restrict__ z0,
                                                const int* __restrict__ flags) {
    __shared__ float xl[LP1][VV];
    __shared__ float A_sh[VV][VV + 1];
    __shared__ float Bl_sh[VV][12];
    __shared__ float var_sh[VV * HH];
    __shared__ float temp_sh[LP1 * HH];
    int isbf = flags[0];
    int tid = threadIdx.x;
    int bt = blockIdx.x; int b = bt >> 8; int t = bt & 255;

    stage(var_sh, var_emb, VV * HH, isbf, tid, 256);
    stage(temp_sh, temp_emb, LP1 * HH, isbf, tid, 256);
    for (int p = tid; p < LP1 * VV; p += 256) {
        int l = p >> 6, s = p & 63; int tt = t - l;
        xl[l][s] = (tt >= 0) ? ldf(x, (size_t)(b * SS + tt) * VV + s, isbf) : 0.f;
    }
    __syncthreads();

    for (int p = tid; p < VV * VV; p += 256) {
        int i = p & 63, s = p >> 6;
        const float* ap = adj + (s * VV + i) * LP1;
        float acc = 0.f;
        #pragma unroll
        for (int l = 0; l < LP1; l++) acc += xl[l][s] * ap[l];
        A_sh[i][s] = acc;
    }
    for (int p = tid; p < VV * LP1; p += 256) {
        int i = p & 63, l = p >> 6;
        float acc = 0.f;
        for (int s = 0; s < VV; s++) acc += xl[l][s] * adj[(s * VV + i) * LP1 + l];
        Bl_sh[i][l] = acc;
    }
    __syncthreads();

    for (int o4 = tid; o4 < VV * HH / 4; o4 += 256) {
        int i = o4 >> 5; int h0 = (o4 & 31) * 4;
        float4 acc = make_float4(0.f, 0.f, 0.f, 0.f);
        for (int s = 0; s < VV; s++) {
            float a = A_sh[i][s];
            const float4 vv4 = *(const float4*)&var_sh[s * HH + h0];
            acc.x += a * vv4.x; acc.y += a * vv4.y; acc.z += a * vv4.z; acc.w += a * vv4.w;
        }
        #pragma unroll
        for (int l = 0; l < LP1; l++) {
            float bl = Bl_sh[i][l];
            const float4 tv = *(const float4*)&temp_sh[l * HH + h0];
            acc.x += bl * tv.x; acc.y += bl * tv.y; acc.z += bl * tv.z; acc.w += bl * tv.w;
        }
        *(float4*)&z0[((size_t)i * BSZ + bt) * HH + h0] = acc;
    }
}

// ---------------- kernel Wp: pre-transpose weights to Wt[n][h] hi/lo bf16 --
// grid = nmat blocks; raw = nmat consecutive 128x128 row-major [h][k] matrices
__global__ __launch_bounds__(256) void k_wprep(const void* __restrict__ raw,
                                               u16* __restrict__ Wh,
                                               u16* __restrict__ Wl,
                                               const int* __restrict__ flags) {
    int isbf = flags[0];
    int mat = blockIdx.x;
    int t = threadIdx.x;
    int kcol = t >> 1, h0 = (t & 1) * 64;
    size_t src = (size_t)mat * (HH * HH);
    size_t dst = src + (size_t)kcol * HH;
    for (int i = 0; i < 64; i++) {
        int h = h0 + i;
        float w = ldf(raw, src + (size_t)h * HH + kcol, isbf);
        u16 hi = f2bf(w);
        Wh[dst + h] = hi;
        Wl[dst + h] = f2bf(w - bfbits2f(hi));
    }
}

// ---------------- kernel G: MFMA GEMM (per-variable 1024x128x128) ----------
// C[v,row,col] = sum_h Z[v,row,h] * W[h,col] + bias; optional LN+GELU.
// mode: 0 = f32 out, 1 = bf16 out, 2 = bias+LN+GELU f32 out
#define LDW 40   // LDS row pitch (u16): 80B, 16B-aligned, 2-way-bank only
__global__ __launch_bounds__(256) void k_gemm(
    const float* __restrict__ zin,
    const u16* __restrict__ Wh, const u16* __restrict__ Wl,
    int nper, int li,
    const void* __restrict__ bias, int bias_base, int bias_stride,
    const void* __restrict__ lngp, const void* __restrict__ lnbp,
    int ln_base, int ln_stride,
    void* __restrict__ outp, int mode,
    const int* __restrict__ flags)
{
    __shared__ u16 Ah_s[128 * LDW];
    __shared__ u16 Al_s[128 * LDW];
    __shared__ u16 Bh_s[128 * LDW];
    __shared__ u16 Bl_s[128 * LDW];
    int isbf = flags[0];
    int tid = threadIdx.x;
    int tile = blockIdx.x, v = blockIdx.y;
    int wave = tid >> 6, lane = tid & 63;
    int quad = lane >> 4, l15 = lane & 15;

    size_t zbase = ((size_t)v * BSZ + (size_t)tile * 128) * HH;
    size_t wbase = (size_t)(v * nper + li) * (HH * HH);

    f32x4 acc[2][8];
    #pragma unroll
    for (int mt = 0; mt < 2; mt++)
        #pragma unroll
        for (int nt = 0; nt < 8; nt++) {
            f32x4 z = {0.f, 0.f, 0.f, 0.f};
            acc[mt][nt] = z;
        }

    for (int c = 0; c < 4; c++) {
        __syncthreads();
        // stage A: Z rows (f32 -> hi/lo bf16), 128 rows x 32 k
        #pragma unroll
        for (int u = 0; u < 4; u++) {
            int p = u * 256 + tid;           // float4 unit among 1024
            int row = p >> 3, kq = p & 7;
            float4 z4 = *(const float4*)&zin[zbase + (size_t)row * HH + c * 32 + kq * 4];
            u16 h0 = f2bf(z4.x), h1 = f2bf(z4.y), h2 = f2bf(z4.z), h3 = f2bf(z4.w);
            u16 l0 = f2bf(z4.x - bfbits2f(h0));
            u16 l1 = f2bf(z4.y - bfbits2f(h1));
            u16 l2 = f2bf(z4.z - bfbits2f(h2));
            u16 l3 = f2bf(z4.w - bfbits2f(h3));
            uint2 hw, lw;
            hw.x = (u32)h0 | ((u32)h1 << 16); hw.y = (u32)h2 | ((u32)h3 << 16);
            lw.x = (u32)l0 | ((u32)l1 << 16); lw.y = (u32)l2 | ((u32)l3 << 16);
            *(uint2*)&Ah_s[row * LDW + kq * 4] = hw;
            *(uint2*)&Al_s[row * LDW + kq * 4] = lw;
        }
        // stage B: Wt rows (bf16 copy), 128 n x 32 k
        #pragma unroll
        for (int u = 0; u < 2; u++) {
            int p = u * 256 + tid;           // 8-elem unit among 512
            int n = p >> 2, k8 = p & 3;
            *(uint4*)&Bh_s[n * LDW + k8 * 8] =
                *(const uint4*)&Wh[wbase + (size_t)n * HH + c * 32 + k8 * 8];
            *(uint4*)&Bl_s[n * LDW + k8 * 8] =
                *(const uint4*)&Wl[wbase + (size_t)n * HH + c * 32 + k8 * 8];
        }
        __syncthreads();

        int m0 = wave * 32;
        s16x8 ah0 = *(const s16x8*)&Ah_s[(m0 + l15) * LDW + quad * 8];
        s16x8 ah1 = *(const s16x8*)&Ah_s[(m0 + 16 + l15) * LDW + quad * 8];
        s16x8 al0 = *(const s16x8*)&Al_s[(m0 + l15) * LDW + quad * 8];
        s16x8 al1 = *(const s16x8*)&Al_s[(m0 + 16 + l15) * LDW + quad * 8];
        #pragma unroll
        for (int nt = 0; nt < 8; nt++) {
            s16x8 bh = *(const s16x8*)&Bh_s[(nt * 16 + l15) * LDW + quad * 8];
            s16x8 bl = *(const s16x8*)&Bl_s[(nt * 16 + l15) * LDW + quad * 8];
            acc[0][nt] = __builtin_amdgcn_mfma_f32_16x16x32_bf16(ah0, bh, acc[0][nt], 0, 0, 0);
            acc[0][nt] = __builtin_amdgcn_mfma_f32_16x16x32_bf16(al0, bh, acc[0][nt], 0, 0, 0);
            acc[0][nt] = __builtin_amdgcn_mfma_f32_16x16x32_bf16(ah0, bl, acc[0][nt], 0, 0, 0);
            acc[1][nt] = __builtin_amdgcn_mfma_f32_16x16x32_bf16(ah1, bh, acc[1][nt], 0, 0, 0);
            acc[1][nt] = __builtin_amdgcn_mfma_f32_16x16x32_bf16(al1, bh, acc[1][nt], 0, 0, 0);
            acc[1][nt] = __builtin_amdgcn_mfma_f32_16x16x32_bf16(ah1, bl, acc[1][nt], 0, 0, 0);
        }
    }

    // ---- epilogue: bias (+ LN + GELU), write ----
    float bcol[8], gcol[8], b2col[8];
    #pragma unroll
    for (int nt = 0; nt < 8; nt++) {
        int col = nt * 16 + l15;
        bcol[nt] = ldf(bias, (size_t)bias_base + (size_t)v * bias_stride + col, isbf);
        if (mode == 2) {
            gcol[nt]  = ldf(lngp, (size_t)ln_base + (size_t)v * ln_stride + col, isbf);
            b2col[nt] = ldf(lnbp, (size_t)ln_base + (size_t)v * ln_stride + col, isbf);
        }
    }
    #pragma unroll
    for (int mt = 0; mt < 2; mt++) {
        #pragma unroll
        for (int r = 0; r < 4; r++) {
            float vals[8];
            float sum = 0.f, sq = 0.f;
            #pragma unroll
            for (int nt = 0; nt < 8; nt++) {
                float val = acc[mt][nt][r] + bcol[nt];
                vals[nt] = val; sum += val; sq += val * val;
            }
            if (mode == 2) {
                #pragma unroll
                for (int m = 1; m < 16; m <<= 1) {
                    sum += __shfl_xor(sum, m);
                    sq  += __shfl_xor(sq, m);
                }
                float mean = sum * (1.f / HH);
                float var  = sq * (1.f / HH) - mean * mean;
                float rstd = rsqrtf(var + 1e-5f);
                #pragma unroll
                for (int nt = 0; nt < 8; nt++) {
                    float y = (vals[nt] - mean) * rstd * gcol[nt] + b2col[nt];
                    vals[nt] = 0.5f * y * (1.f + erff(y * 0.70710678118654752f));
                }
            }
            int row = tile * 128 + wave * 32 + mt * 16 + quad * 4 + r;
            size_t ob = ((size_t)v * BSZ + row) * HH;
            if (mode == 1) {
                u16* o16 = (u16*)outp;
                #pragma unroll
                for (int nt = 0; nt < 8; nt++) o16[ob + nt * 16 + l15] = f2bf(vals[nt]);
            } else {
                float* of = (float*)outp;
                #pragma unroll
                for (int nt = 0; nt < 8; nt++) of[ob + nt * 16 + l15] = vals[nt];
            }
        }
    }
}

// ---------------- kernel 5: attention, single pass, no max -----------------
// scores s*0.25 are O(few sigma) (LN-bounded) -> exp cannot overflow f32.
__global__ __launch_bounds__(256) void k_attn(float* __restrict__ Q,
                                              const u16* __restrict__ K16,
                                              const u16* __restrict__ V16) {
    __shared__ float K_sh[SS * DHH];
    __shared__ float V_sh[SS * DHH];
    int tid = threadIdx.x;
    int bn = blockIdx.x, v = blockIdx.y;
    int b = bn >> 3, n = bn & 7;

    for (int p = tid; p < SS * DHH; p += 256) {
        int j = p >> 4, d = p & 15;
        size_t src = ((size_t)v * BSZ + b * SS + j) * HH + n * DHH + d;
        K_sh[p] = bfbits2f(K16[src]);
        V_sh[p] = bfbits2f(V16[src]);
    }
    float* qrow = Q + ((size_t)v * BSZ + b * SS + tid) * HH + n * DHH;
    const float4* qp = (const float4*)qrow;
    float4 q0 = qp[0], q1 = qp[1], q2 = qp[2], q3 = qp[3];
    __syncthreads();

    float l = 0.f;
    float4 o0 = make_float4(0,0,0,0), o1 = make_float4(0,0,0,0);
    float4 o2 = make_float4(0,0,0,0), o3 = make_float4(0,0,0,0);
    for (int j = 0; j < SS; j++) {
        const float4* kr = (const float4*)&K_sh[j * DHH];
        float4 ka = kr[0], kb = kr[1], kc = kr[2], kd = kr[3];
        float s = q0.x * ka.x + q0.y * ka.y + q0.z * ka.z + q0.w * ka.w
                + q1.x * kb.x + q1.y * kb.y + q1.z * kb.z + q1.w * kb.w
                + q2.x * kc.x + q2.y * kc.y + q2.z * kc.z + q2.w * kc.w
                + q3.x * kd.x + q3.y * kd.y + q3.z * kd.z + q3.w * kd.w;
        float w = __expf(s * 0.25f);
        l += w;
        const float4* vr = (const float4*)&V_sh[j * DHH];
        float4 va = vr[0], vb = vr[1], vc = vr[2], vd = vr[3];
        o0.x += w * va.x; o0.y += w * va.y; o0.z += w * va.z; o0.w += w * va.w;
        o1.x += w * vb.x; o1.y += w * vb.y; o1.z += w * vb.z; o1.w += w * vb.w;
        o2.x += w * vc.x; o2.y += w * vc.y; o2.z += w * vc.z; o2.w += w * vc.w;
        o3.x += w * vd.x; o3.y += w * vd.y; o3.z += w * vd.z; o3.w += w * vd.w;
    }
    float inv = 1.f / l;
    float4* qw = (float4*)qrow;
    qw[0] = make_float4(o0.x*inv, o0.y*inv, o0.z*inv, o0.w*inv);
    qw[1] = make_float4(o1.x*inv, o1.y*inv, o1.z*inv, o1.w*inv);
    qw[2] = make_float4(o2.x*inv, o2.y*inv, o2.z*inv, o2.w*inv);
    qw[3] = make_float4(o3.x*inv, o3.y*inv, o3.z*inv, o3.w*inv);
}

// ---------------- kernel 6: fused output head ------------------------------
__global__ __launch_bounds__(256) void k_final(const float* __restrict__ o,
                                               const float* __restrict__ wfused,
                                               const float* __restrict__ bfused,
                                               void* __restrict__ out,
                                               const int* __restrict__ flags) {
    __shared__ float wf[HH];
    int isbf = flags[0];
    int tid = threadIdx.x; int b = blockIdx.x; int v = blockIdx.y;
    if (tid < HH) wf[tid] = wfused[v * HH + tid];
    __syncthreads();
    int bt = b * SS + tid;
    const float* orow = o + ((size_t)v * BSZ + bt) * HH;
    float acc = 0.f;
    #pragma unroll 8
    for (int h4 = 0; h4 < HH / 4; h4++) {
        float4 ov = ((const float4*)orow)[h4];
        const float4 wv = *(const float4*)&wf[h4 * 4];
        acc += ov.x * wv.x + ov.y * wv.y + ov.z * wv.z + ov.w * wv.w;
    }
    float pred = acc + bfused[v];
    size_t oi = (size_t)bt * VV + v;
    if (isbf) ((u16*)out)[oi] = f2bf(pred);
    else      ((float*)out)[oi] = pred;
}

extern "C" void kernel_launch(void* const* d_in, const int* in_sizes, int n_in,
                              void* d_out, int out_size, void* d_ws, size_t ws_size,
                              hipStream_t stream) {
    (void)out_size; (void)ws_size;

    // ---- resolve input permutation from in_sizes (host-side, capture-safe) ----
    static const int dict_sizes[18]  = {65536,45056,8192,1408,3145728,24576,24576,24576,
                                        1048576,1048576,1048576,1048576,8192,8192,8192,8192,8192,64};
    static const int alpha_sizes[18] = {1048576,1048576,1048576,1048576,45056,8192,8192,8192,
                                        8192,24576,24576,3145728,24576,8192,64,1408,8192,65536};
    static const int alpha_pos[18]   = {17,4,16,15,11,12,10,9,2,0,3,1,7,5,8,6,13,14};
    static const int alpha_logical[18] = {9,11,8,10,1,13,15,12,14,7,6,4,5,16,17,3,2,0};

    const void* in[18];
    bool is_dict = (n_in == 18), is_alpha = (n_in == 18);
    for (int i = 0; i < 18 && i < n_in; i++) {
        if (in_sizes[i] != dict_sizes[i])  is_dict = false;
        if (in_sizes[i] != alpha_sizes[i]) is_alpha = false;
    }
    if (is_dict) {
        for (int i = 0; i < 18; i++) in[i] = d_in[i];
    } else if (is_alpha) {
        for (int i = 0; i < 18; i++) in[i] = d_in[alpha_pos[i]];
    } else {
        bool used[18] = {false};
        for (int a = 0; a < 18; a++) {
            int lg = alpha_logical[a];
            for (int i = 0; i < n_in && i < 18; i++) {
                if (!used[i] && in_sizes[i] == dict_sizes[lg]) {
                    in[lg] = d_in[i]; used[i] = true; break;
                }
            }
        }
    }

    const void* x        = in[0];
    const void* adjl     = in[1];
    const void* var_emb  = in[2];
    const void* temp_emb = in[3];
    const void* mechW    = in[4];
    const void* mechb    = in[5];
    const void* lng      = in[6];
    const void* lnb      = in[7];
    const void* Wq       = in[8];
    const void* Wk       = in[9];
    const void* Wv       = in[10];
    const void* Wo       = in[11];
    const void* bq       = in[12];
    const void* bk       = in[13];
    const void* bv       = in[14];
    const void* bo       = in[15];
    const void* outW     = in[16];
    const void* outb     = in[17];

    // workspace (floats), total ~126 MB
    float* ws     = (float*)d_ws;
    int*   flags  = (int*)ws;                 // 32 slots
    float* adj    = ws + 32;                  // 45056
    float* wfused = ws + 45088;               // 8192
    float* bfused = ws + 53280;               // 64
    float* zA     = ws + 53376;               // 8388608 (V,BS,H) f32
    float* zB     = zA + 8388608;             // -> 16830592
    u16*   K16    = (u16*)(ws + 16830592);    // 8388608 u16
    u16*   V16    = (u16*)(ws + 21024896);    // 8388608 u16
    u16*   WtmH   = (u16*)(ws + 25219200);    // 192*16384 u16
    u16*   WtmL   = (u16*)(ws + 26792064);
    u16*   WtqH   = (u16*)(ws + 28364928);    // 64*16384 u16 each below
    u16*   WtqL   = (u16*)(ws + 28889216);
    u16*   WtkH   = (u16*)(ws + 29413504);
    u16*   WtkL   = (u16*)(ws + 29937792);
    u16*   WtvH   = (u16*)(ws + 30462080);
    u16*   WtvL   = (u16*)(ws + 30986368);    // end 31510656 f = 126.0 MB

    k_sniff <<<dim3(1),    dim3(64),  0, stream>>>((const u16*)mechW, flags);
    k_adj   <<<dim3(176),  dim3(256), 0, stream>>>(adjl, adj, flags);
    k_fuse  <<<dim3(64),   dim3(128), 0, stream>>>(Wo, outW, bo, outb, wfused, bfused, flags);
    k_causal<<<dim3(BSZ),  dim3(256), 0, stream>>>(x, adj, var_emb, temp_emb, zA, flags);

    k_wprep <<<dim3(192),  dim3(256), 0, stream>>>(mechW, WtmH, WtmL, flags);
    k_wprep <<<dim3(64),   dim3(256), 0, stream>>>(Wq, WtqH, WtqL, flags);
    k_wprep <<<dim3(64),   dim3(256), 0, stream>>>(Wk, WtkH, WtkL, flags);
    k_wprep <<<dim3(64),   dim3(256), 0, stream>>>(Wv, WtvH, WtvL, flags);

    // mech layers (mode 2: bias+LN+GELU)
    k_gemm<<<dim3(8, 64), dim3(256), 0, stream>>>(zA, WtmH, WtmL, NLL, 0,
            mechb, 0 * HH, NLL * HH, lng, lnb, 0 * HH, NLL * HH, zB, 2, flags);
    k_gemm<<<dim3(8, 64), dim3(256), 0, stream>>>(zB, WtmH, WtmL, NLL, 1,
            mechb, 1 * HH, NLL * HH, lng, lnb, 1 * HH, NLL * HH, zA, 2, flags);
    k_gemm<<<dim3(8, 64), dim3(256), 0, stream>>>(zA, WtmH, WtmL, NLL, 2,
            mechb, 2 * HH, NLL * HH, lng, lnb, 2 * HH, NLL * HH, zB, 2, flags);

    // QKV projections
    k_gemm<<<dim3(8, 64), dim3(256), 0, stream>>>(zB, WtqH, WtqL, 1, 0,
            bq, 0, HH, lng, lnb, 0, 0, zA, 0, flags);
    k_gemm<<<dim3(8, 64), dim3(256), 0, stream>>>(zB, WtkH, WtkL, 1, 0,
            bk, 0, HH, lng, lnb, 0, 0, K16, 1, flags);
    k_gemm<<<dim3(8, 64), dim3(256), 0, stream>>>(zB, WtvH, WtvL, 1, 0,
            bv, 0, HH, lng, lnb, 0, 0, V16, 1, flags);

    k_attn  <<<dim3(BB * NHH, VV), dim3(256), 0, stream>>>(zA, K16, V16);
    k_final <<<dim3(BB, VV), dim3(256), 0, stream>>>(zA, wfused, bfused, d_out, flags);
}